// Round 5
// baseline (452.629 us; speedup 1.0000x reference)
//
#include <hip/hip_runtime.h>

typedef unsigned int u32;
typedef __attribute__((ext_vector_type(8))) _Float16 half8;
typedef __attribute__((ext_vector_type(4))) _Float16 half4;
typedef __attribute__((ext_vector_type(4))) float floatx4;

#define DEVI __device__ __forceinline__

// ---------- async global->LDS (16B per lane), m97-style ----------
DEVI void gload_lds16(const _Float16* g, _Float16* l) {
    __builtin_amdgcn_global_load_lds(
        (const __attribute__((address_space(1))) void*)g,
        (__attribute__((address_space(3))) void*)l, 16, 0, 0);
}

// Stage a 128x64 fp16 tile (16 KB) from global (row stride ldg halfs) into LDS.
// XOR-swizzled at 8-half chunk granularity: LDS(r, p) holds global chunk
// c = p ^ (r&7); global source address permuted per lane (global_load_lds
// needs lane-ordered dest). Readback conflict-free (R3/R4: bank conflicts = 0).
DEVI void stage128(const _Float16* __restrict__ g, int ldg, _Float16* lds, int tid) {
#pragma unroll
    for (int it = 0; it < 4; ++it) {
        int s = it * 256 + tid;       // slot: 1024 slots of 8 halfs
        int r = s >> 3, p = s & 7;
        int c = p ^ (r & 7);
        gload_lds16(g + (size_t)r * ldg + c * 8, lds + (size_t)s * 8);
    }
}

// read 8 halfs of row r starting at column ko (ko multiple of 8)
DEVI half8 frag(const _Float16* lds, int r, int ko) {
    return *(const half8*)&lds[r * 64 + (((ko >> 3) ^ (r & 7)) << 3)];
}

// A frag: A[m][k], m=lane&15, k=(lane>>4)*8+j ; B frag: B[k][n], n=lane&15
// C/D: col=lane&15, row=(lane>>4)*4+reg   (verified layouts, guide §3)
DEVI void mfma1_128(const _Float16* LA, const _Float16* LB,
                    floatx4 acc[4][4], int wm, int wn, int lane) {
    const int lr = lane & 15, quad = lane >> 4;
#pragma unroll
    for (int kk = 0; kk < 64; kk += 32) {
        const int ko = kk + quad * 8;
        half8 a[4], b[4];
#pragma unroll
        for (int i = 0; i < 4; ++i) {
            a[i] = frag(LA, wm * 64 + i * 16 + lr, ko);
            b[i] = frag(LB, wn * 64 + i * 16 + lr, ko);
        }
#pragma unroll
        for (int mi = 0; mi < 4; ++mi)
#pragma unroll
            for (int ni = 0; ni < 4; ++ni)
                acc[mi][ni] = __builtin_amdgcn_mfma_f32_16x16x32_f16(a[mi], b[ni], acc[mi][ni], 0, 0, 0);
    }
}

// XCD-locality supertile swizzle: dispatch-linear id -> (mt, nt) with m-chunks
// of 8 so XCD j (round-robin id%8) keeps re-reading one A row-strip while B
// streams. Requires gx % 8 == 0 (all our grids satisfy; guarded anyway).
DEVI void swizzle_mn(int gx, int gy, int& mt, int& nt) {
    int id = blockIdx.x + blockIdx.y * gx;
    if ((gx & 7) == 0) {
        int per = 8 * gy;
        int chunk = id / per, rem = id % per;
        mt = chunk * 8 + (rem & 7);
        nt = rem >> 3;
    } else {
        mt = blockIdx.x; nt = blockIdx.y;
    }
}

// ---------------- merged prep: cast x, transpose+cast w, cast ow ----------------
// grid: [0,8192) cast x (8 f32->f16 per thread); [8192,11264) w transpose;
// [11264,11776) ow cast.
__global__ __launch_bounds__(256) void k_prep(
    const float* __restrict__ x, _Float16* __restrict__ xh,
    const float* __restrict__ wq, _Float16* __restrict__ wh,
    const float* __restrict__ ow, _Float16* __restrict__ owh)
{
    __shared__ float tile[32][33];
    const int bid = blockIdx.x, t = threadIdx.x;
    if (bid < 8192) {
        size_t i = ((size_t)bid * 256 + t) * 8;
        float4 v0 = *(const float4*)(x + i);
        float4 v1 = *(const float4*)(x + i + 4);
        float vv[8] = {v0.x, v0.y, v0.z, v0.w, v1.x, v1.y, v1.z, v1.w};
        half8 h;
#pragma unroll
        for (int j = 0; j < 8; ++j) h[j] = (_Float16)vv[j];
        *(half8*)(xh + i) = h;
    } else if (bid < 11264) {
        int id = bid - 8192;
        const int n0 = (id % 96) * 32, k0 = (id / 96) * 32;
#pragma unroll
        for (int it = 0; it < 4; ++it) {
            int idx = it * 256 + t;
            int kk = idx >> 5, nn = idx & 31;
            tile[kk][nn] = wq[(size_t)(k0 + kk) * 3072 + n0 + nn];
        }
        __syncthreads();
#pragma unroll
        for (int it = 0; it < 4; ++it) {
            int idx = it * 256 + t;
            int nn = idx >> 5, kk = idx & 31;
            wh[(size_t)(n0 + nn) * 1024 + k0 + kk] = (_Float16)tile[kk][nn];
        }
    } else {
        int id = bid - 11264;
        size_t i = ((size_t)id * 256 + t) * 8;
        float4 v0 = *(const float4*)(ow + i);
        float4 v1 = *(const float4*)(ow + i + 4);
        float vv[8] = {v0.x, v0.y, v0.z, v0.w, v1.x, v1.y, v1.z, v1.w};
        half8 h;
#pragma unroll
        for (int j = 0; j < 8; ++j) h[j] = (_Float16)vv[j];
        *(half8*)(owh + i) = h;
    }
}

// ---------------- qkv GEMM, 128x128 tile, uniform fp16 K=1024 ----------------
__global__ __launch_bounds__(256, 3) void k_qkv(
    const _Float16* __restrict__ xh, const _Float16* __restrict__ wh,
    _Float16* __restrict__ qh, _Float16* __restrict__ kh, _Float16* __restrict__ vT)
{
    __shared__ __align__(16) _Float16 LA[128 * 64], LB[128 * 64];
    int mt, nt;
    swizzle_mn(gridDim.x, gridDim.y, mt, nt);
    const int m0 = mt * 128, n0 = nt * 128;
    const int tid = threadIdx.x, lane = tid & 63, w = tid >> 6, wm = w >> 1, wn = w & 1;
    floatx4 acc[4][4];
    const floatx4 zf = {0.f, 0.f, 0.f, 0.f};
#pragma unroll
    for (int mi = 0; mi < 4; ++mi)
        for (int ni = 0; ni < 4; ++ni) acc[mi][ni] = zf;

    const _Float16* A = xh + (size_t)m0 * 1024;
    const _Float16* B = wh + (size_t)n0 * 1024;
    for (int kt = 0; kt < 16; ++kt) {
        stage128(A + kt * 64, 1024, LA, tid);
        stage128(B + kt * 64, 1024, LB, tid);
        __syncthreads();
        mfma1_128(LA, LB, acc, wm, wn, lane);
        __syncthreads();
    }

    const int lr = lane & 15, quad = lane >> 4;
    if (n0 < 1024) {            // q, scaled by 1/sqrt(1024)
#pragma unroll
        for (int mi = 0; mi < 4; ++mi)
            for (int ni = 0; ni < 4; ++ni)
                for (int r = 0; r < 4; ++r) {
                    int m = m0 + wm * 64 + mi * 16 + quad * 4 + r;
                    int n = n0 + wn * 64 + ni * 16 + lr;
                    qh[(size_t)m * 1024 + n] = (_Float16)(acc[mi][ni][r] * 0.03125f);
                }
    } else if (n0 < 2048) {     // k
#pragma unroll
        for (int mi = 0; mi < 4; ++mi)
            for (int ni = 0; ni < 4; ++ni)
                for (int r = 0; r < 4; ++r) {
                    int m = m0 + wm * 64 + mi * 16 + quad * 4 + r;
                    int n = n0 - 1024 + wn * 64 + ni * 16 + lr;
                    kh[(size_t)m * 1024 + n] = (_Float16)acc[mi][ni][r];
                }
    } else {                    // v, written transposed: vT[b][e][n-in-seq]
#pragma unroll
        for (int mi = 0; mi < 4; ++mi)
            for (int ni = 0; ni < 4; ++ni) {
                int mb = m0 + wm * 64 + mi * 16 + quad * 4;   // 4-aligned
                int b = mb >> 11, ml = mb & 2047;
                int e = n0 - 2048 + wn * 64 + ni * 16 + lr;
                half4 pk;
#pragma unroll
                for (int r = 0; r < 4; ++r) pk[r] = (_Float16)acc[mi][ni][r];
                *(half4*)&vT[((size_t)b * 1024 + e) * 2048 + ml] = pk;
            }
    }
}

// ---------------- generic 128x128 fp16 GEMM (A,B row-major contiguous-K) ----------------
// EPI 0: fp16 out at C16[z*sCz + m*ldc + n]; EPI 1: fp32 out + bias at C32[m*ldc + n]
template <int EPI>
__global__ __launch_bounds__(256, 3) void k_gemm128(
    const _Float16* __restrict__ Ab, const _Float16* __restrict__ Bb,
    _Float16* __restrict__ C16, float* __restrict__ C32, const float* __restrict__ bias,
    int K, unsigned long long sAz, unsigned long long sBz, unsigned long long sCz, int ldc)
{
    __shared__ __align__(16) _Float16 LA[128 * 64], LB[128 * 64];
    const int z = blockIdx.z;
    int mt, nt;
    swizzle_mn(gridDim.x, gridDim.y, mt, nt);
    const int m0 = mt * 128, n0 = nt * 128;
    const _Float16* A = Ab + (size_t)z * sAz + (size_t)m0 * K;
    const _Float16* B = Bb + (size_t)z * sBz + (size_t)n0 * K;
    const int tid = threadIdx.x, lane = tid & 63, w = tid >> 6, wm = w >> 1, wn = w & 1;
    floatx4 acc[4][4];
    const floatx4 zf = {0.f, 0.f, 0.f, 0.f};
#pragma unroll
    for (int mi = 0; mi < 4; ++mi)
        for (int ni = 0; ni < 4; ++ni) acc[mi][ni] = zf;
    const int nkt = K >> 6;
    for (int kt = 0; kt < nkt; ++kt) {
        stage128(A + kt * 64, K, LA, tid);
        stage128(B + kt * 64, K, LB, tid);
        __syncthreads();
        mfma1_128(LA, LB, acc, wm, wn, lane);
        __syncthreads();
    }
    const int lr = lane & 15, quad = lane >> 4;
#pragma unroll
    for (int mi = 0; mi < 4; ++mi)
#pragma unroll
        for (int ni = 0; ni < 4; ++ni)
#pragma unroll
            for (int r = 0; r < 4; ++r) {
                int m = m0 + wm * 64 + mi * 16 + quad * 4 + r;
                int n = n0 + wn * 64 + ni * 16 + lr;
                if (EPI == 0)
                    C16[(size_t)z * sCz + (size_t)m * ldc + n] = (_Float16)acc[mi][ni][r];
                else
                    C32[(size_t)m * ldc + n] = acc[mi][ni][r] + bias[n];
            }
}

// ---------------- softmax rows, fp16 in place, vectorized half8 ----------------
DEVI float wred_max(float v) {
#pragma unroll
    for (int o = 32; o; o >>= 1) v = fmaxf(v, __shfl_xor(v, o, 64));
    return v;
}
DEVI float wred_sum(float v) {
#pragma unroll
    for (int o = 32; o; o >>= 1) v += __shfl_xor(v, o, 64);
    return v;
}

__global__ __launch_bounds__(256) void k_softmax(_Float16* __restrict__ S) {
    const size_t row = blockIdx.x;
    _Float16* p = S + row * 2048;
    const int t = threadIdx.x;
    __shared__ float redm[4], reds[4];
    half8 hv = *(const half8*)(p + t * 8);   // one 16B load per lane, coalesced
    float v[8];
    float mx = -3.4e38f;
#pragma unroll
    for (int i = 0; i < 8; ++i) { v[i] = (float)hv[i]; mx = fmaxf(mx, v[i]); }
    mx = wred_max(mx);
    if ((t & 63) == 0) redm[t >> 6] = mx;
    __syncthreads();
    mx = fmaxf(fmaxf(redm[0], redm[1]), fmaxf(redm[2], redm[3]));
    float s = 0.f;
#pragma unroll
    for (int i = 0; i < 8; ++i) { v[i] = __expf(v[i] - mx); s += v[i]; }
    s = wred_sum(s);
    if ((t & 63) == 0) reds[t >> 6] = s;
    __syncthreads();
    s = reds[0] + reds[1] + reds[2] + reds[3];
    float inv = 1.0f / s;
#pragma unroll
    for (int i = 0; i < 8; ++i) hv[i] = (_Float16)(v[i] * inv);
    *(half8*)(p + t * 8) = hv;               // one 16B store per lane
}

// ---------------- launch ----------------
extern "C" void kernel_launch(void* const* d_in, const int* in_sizes, int n_in,
                              void* d_out, int out_size, void* d_ws, size_t ws_size,
                              hipStream_t stream) {
    const float* x  = (const float*)d_in[0];   // [8,2048,1024]
    const float* wq = (const float*)d_in[1];   // [1024,3072]
    const float* ow = (const float*)d_in[2];   // [1024,1024]
    const float* ob = (const float*)d_in[3];   // [1024]
    float* out = (float*)d_out;                // [8,2048,1024] fp32

    // workspace layout (bytes), guard at R2/R3-proven 172 MB
    char* ws = (char*)d_ws;
    _Float16* xh  = (_Float16*)(ws + 0);           // 32 MB [16384][1024] (dead after qkv)
    _Float16* wh  = (_Float16*)(ws + 33554432);    // 6 MB [3072][1024]   (dead after qkv)
    _Float16* S   = (_Float16*)(ws + 0);           // 64 MB [8][2048][2048] over xh+wh
    _Float16* qh  = (_Float16*)(ws + 67108864);    // 32 MB (scaled 1/32)
    _Float16* kh  = (_Float16*)(ws + 100663296);   // 32 MB
    _Float16* vT  = (_Float16*)(ws + 134217728);   // 32 MB [8][1024][2048]
    _Float16* owh = (_Float16*)(ws + 167772160);   // 2 MB
    _Float16* y   = qh;                            // qh dead after S-gemm

    if (ws_size < 180355072ull) return;  // clean fail instead of OOB corruption

    hipLaunchKernelGGL(k_prep, dim3(11776), dim3(256), 0, stream, x, xh, wq, wh, ow, owh);
    hipLaunchKernelGGL(k_qkv, dim3(128, 24), dim3(256), 0, stream, xh, wh, qh, kh, vT);
    // S = q k^T  (over dead xh/wh region)
    hipLaunchKernelGGL((k_gemm128<0>), dim3(16, 16, 8), dim3(256), 0, stream,
                       qh, kh, S, (float*)nullptr, (const float*)nullptr,
                       1024, 2048ull * 1024, 2048ull * 1024, 2048ull * 2048, 2048);
    hipLaunchKernelGGL(k_softmax, dim3(16384), dim3(256), 0, stream, S);
    // y = P V   (y over dead qh region)
    hipLaunchKernelGGL((k_gemm128<0>), dim3(16, 8, 8), dim3(256), 0, stream,
                       S, vT, y, (float*)nullptr, (const float*)nullptr,
                       2048, 2048ull * 2048, 1024ull * 2048, 2048ull * 1024, 1024);
    // out = y ow^T + b
    hipLaunchKernelGGL((k_gemm128<1>), dim3(128, 8, 1), dim3(256), 0, stream,
                       y, owh, (_Float16*)nullptr, out, ob,
                       1024, 0ull, 0ull, 0ull, 1024);
}